// Round 4
// baseline (164.006 us; speedup 1.0000x reference)
//
#include <hip/hip_runtime.h>
#include <math.h>

#define E_TOTAL 32768
#define NUM_NODES 4096
#define SCALE 0.70710678118654752f

typedef __attribute__((ext_vector_type(8))) short bfrag;
typedef __attribute__((ext_vector_type(16))) float facc;

__device__ inline unsigned short f2bf(float f) {
  unsigned int u = __float_as_uint(f);
  unsigned int r = (u + 0x7FFFu + ((u >> 16) & 1u)) >> 16;
  return (unsigned short)r;
}
__device__ inline float bf2f(unsigned short s) {
  return __uint_as_float(((unsigned int)s) << 16);
}
__device__ inline void cvt8(const float* v, bfrag& hi, bfrag& lo) {
#pragma unroll
  for (int i = 0; i < 8; ++i) {
    unsigned short h = f2bf(v[i]);
    hi[i] = (short)h;
    lo[i] = (short)f2bf(v[i] - bf2f(h));
  }
}

// async global->LDS, 16 B per lane, wave-uniform LDS base + lane*16
__device__ inline void stage16(const void* g, void* l) {
  __builtin_amdgcn_global_load_lds(
      (const __attribute__((address_space(1))) unsigned int*)g,
      (__attribute__((address_space(3))) unsigned int*)l, 16, 0, 0);
}

// ---------------------------------------------------------------------------
// Combined prep: blocks 0..95 W_p frags, 96..102 W_q frags, 103..230 offsets
// frag layout per n-tile nt=c*6+w: [ks(4)][hl(2)][lane(64)][j(8)] bf16 (8 KB)
//   element = W_p[d][w*512 + c*32 + (lane&31)], d = ks*16 + (lane>>5)*8 + j
// ---------------------------------------------------------------------------
__global__ __launch_bounds__(256) void prep_kernel(
    const float* __restrict__ Wp, const float* __restrict__ Wq,
    const int* __restrict__ index,
    unsigned short* __restrict__ fragWp, unsigned short* __restrict__ fragWq,
    int* __restrict__ offs)
{
  const int b = blockIdx.x, t = threadIdx.x;
  if (b < 96) {
    __shared__ unsigned short lds[4096];
    const int c = b / 6, w = b - c * 6;
    const int colbase = w * 512 + c * 32;
    const int cl = t & 31, dg = t >> 5;
#pragma unroll
    for (int i = 0; i < 8; ++i) {
      const int d = dg * 8 + i;
      const float v = Wp[(size_t)d * 3072 + colbase + cl];
      const unsigned short hi = f2bf(v);
      const unsigned short lo = f2bf(v - bf2f(hi));
      const int ks = d >> 4;
      const int lane = ((d >> 3) & 1) * 32 + cl;
      const int j = d & 7;
      lds[(ks * 2 + 0) * 512 + lane * 8 + j] = hi;
      lds[(ks * 2 + 1) * 512 + lane * 8 + j] = lo;
    }
    __syncthreads();
    unsigned short* dst = fragWp + (size_t)b * 4096;
    ((uint4*)dst)[t] = ((const uint4*)lds)[t];
    ((uint4*)dst)[t + 256] = ((const uint4*)lds)[t + 256];
  } else if (b < 103) {
    const int slot = b - 96;
    const int w = (slot == 6) ? 5 : slot;
    const float sgn = (slot == 6) ? -1.f : 1.f;
    for (int tt = t; tt < 512; tt += 256) {
      const int lane = tt >> 3, j = tt & 7;
      const int o = lane & 31, c = (lane >> 5) * 8 + j;
      const float v = sgn * Wq[(size_t)(w * 16 + c) * 32 + o];
      const unsigned short hi = f2bf(v);
      const unsigned short lo = f2bf(v - bf2f(hi));
      fragWq[slot * 1024 + lane * 8 + j] = hi;
      fragWq[slot * 1024 + 512 + lane * 8 + j] = lo;
    }
  } else {
    const int tg = (b - 103) * 256 + t;
    if (tg >= E_TOTAL) return;
    const int cur = index[tg];
    const int prev = (tg == 0) ? -1 : index[tg - 1];
    for (int n = prev + 1; n <= cur; ++n) offs[n] = tg;
    if (tg == E_TOTAL - 1)
      for (int n = cur + 1; n <= NUM_NODES; ++n) offs[n] = E_TOTAL;
  }
}

// ---------------------------------------------------------------------------
// Main: 256 blocks (1/CU), 4 waves, 128 edges/block, 32 edges/wave.
// LDS-staged W stream with a COUNTED-vmcnt pipeline (T3+T4): DEPTH=4 tile
// buffers, 3 stages in flight, ONE raw s_barrier per tile, never vmcnt(0)
// in the loop. Per phase: stage(k+3); vmcnt(4)+lgkmcnt(0); barrier; fence;
// ds_read(k+1) into alternate reg set (overlaps MFMA(k) below); MFMA(k)+so2.
// lgkmcnt(0) before each barrier = cross-wave proof that tile k-1's reads
// retired before anyone overwrites its buffer with stage(k+3).
// ---------------------------------------------------------------------------
__global__ __launch_bounds__(256, 1) void main_kernel(
    const float* __restrict__ x_q, const float* __restrict__ x_k,
    const float* __restrict__ emb,
    const unsigned short* __restrict__ fragWp,
    const unsigned short* __restrict__ fragWq,
    float* __restrict__ z)
{
  __shared__ float xk_t[64][129];                       // 33 KB, padded
  __shared__ alignas(16) unsigned short wbuf[4][4096];  // 4 x 8 KB tile ring

  const int t = threadIdx.x;
  const int lane = t & 63, wv = t >> 6;
  const int col = lane & 31, half = lane >> 5;
  const int eb = blockIdx.x * 128;
  const int el = wv * 32 + col;
  const int e = eb + el;

  // issue stages for tiles 0,1,2 ASAP (drained by the prologue syncthreads)
#pragma unroll
  for (int pt = 0; pt < 3; ++pt) {
    const char* tb = (const char*)fragWp + (size_t)pt * 8192;
    char* db = (char*)&wbuf[pt][0];
    stage16(tb + (wv * 2 + 0) * 1024 + lane * 16, db + (wv * 2 + 0) * 1024);
    stage16(tb + (wv * 2 + 1) * 1024 + lane * 16, db + (wv * 2 + 1) * 1024);
  }

  // stage x_k transposed: thread t -> edge t&127, d-half (t>>7)*32
  {
    const int er = t & 127, dh = (t >> 7) * 32;
    const float* src = x_k + (size_t)(eb + er) * 64 + dh;
#pragma unroll
    for (int i = 0; i < 8; ++i) {
      float4 v = *(const float4*)(src + i * 4);
      xk_t[dh + i * 4 + 0][er] = v.x;
      xk_t[dh + i * 4 + 1][er] = v.y;
      xk_t[dh + i * 4 + 2][er] = v.z;
      xk_t[dh + i * 4 + 3][er] = v.w;
    }
  }

  // emb B-fragments hi/lo for this wave's 32 edges: B[k=d][col=e]
  bfrag ebh[4], ebl[4];
#pragma unroll
  for (int ks = 0; ks < 4; ++ks) {
    float tmp[8];
    *(float4*)&tmp[0] = *(const float4*)(emb + (size_t)e * 64 + ks * 16 + half * 8);
    *(float4*)&tmp[4] = *(const float4*)(emb + (size_t)e * 64 + ks * 16 + half * 8 + 4);
    cvt8(tmp, ebh[ks], ebl[ks]);
  }

  facc ka0 = {0}, ka1 = {0}, ka2 = {0}, ka3 = {0};

  __syncthreads();  // full drain ONCE: xk_t + tiles 0-2 staged + emb loads done

  // tile 0 fragments -> set A
  bfrag fA[8], fB[8];
  {
    const unsigned short* wb = &wbuf[0][0] + lane * 8;
#pragma unroll
    for (int ks = 0; ks < 4; ++ks) {
      *(uint4*)&fA[ks]     = *(const uint4*)(wb + ks * 1024);
      *(uint4*)&fA[ks + 4] = *(const uint4*)(wb + ks * 1024 + 512);
    }
  }

  float xkc0 = 0.f, xkc1 = 0.f, xkc2 = 0.f, xkc3 = 0.f;

#define PHASE(IT, II, DO_STAGE, VMN_STR, DO_NEXT)                              \
  {                                                                            \
    if (DO_STAGE) {                                                            \
      const char* tb = (const char*)fragWp + (size_t)((IT) + 3) * 8192;        \
      char* db = (char*)&wbuf[((II) + 3) & 3][0];                              \
      stage16(tb + (wv * 2 + 0) * 1024 + lane * 16, db + (wv * 2 + 0) * 1024); \
      stage16(tb + (wv * 2 + 1) * 1024 + lane * 16, db + (wv * 2 + 1) * 1024); \
    }                                                                          \
    asm volatile("s_waitcnt vmcnt(" VMN_STR ") lgkmcnt(0)" ::: "memory");      \
    __builtin_amdgcn_s_barrier();                                              \
    asm volatile("" ::: "memory");                                             \
    if (((II) % 6) == 0) {                                                     \
      const int c16 = (IT) / 6;                                                \
      xkc0 = xk_t[c16][el];      xkc1 = xk_t[16 + c16][el];                    \
      xkc2 = xk_t[32 + c16][el]; xkc3 = xk_t[48 + c16][el];                    \
    }                                                                          \
    bfrag* curf = (((II) & 1) == 0) ? fA : fB;                                 \
    bfrag* nxtf = (((II) & 1) == 0) ? fB : fA;                                 \
    if (DO_NEXT) {                                                             \
      const unsigned short* wb = &wbuf[((II) + 1) & 3][0] + lane * 8;          \
      _Pragma("unroll")                                                        \
      for (int ks = 0; ks < 4; ++ks) {                                         \
        *(uint4*)&nxtf[ks]     = *(const uint4*)(wb + ks * 1024);              \
        *(uint4*)&nxtf[ks + 4] = *(const uint4*)(wb + ks * 1024 + 512);        \
      }                                                                        \
    }                                                                          \
    facc cc0 = {0.f}, cc1 = {0.f}, cc2 = {0.f};                                \
    _Pragma("unroll")                                                          \
    for (int ks = 0; ks < 4; ++ks) {                                           \
      cc0 = __builtin_amdgcn_mfma_f32_32x32x16_bf16(curf[ks], ebh[ks], cc0, 0, 0, 0);     \
      cc1 = __builtin_amdgcn_mfma_f32_32x32x16_bf16(curf[ks], ebl[ks], cc1, 0, 0, 0);     \
      cc2 = __builtin_amdgcn_mfma_f32_32x32x16_bf16(curf[ks + 4], ebh[ks], cc2, 0, 0, 0); \
    }                                                                          \
    const int W = (II) % 6;                                                    \
    if (W < 4) {                                                               \
      const float xv = (W & 2) ? xkc2 : xkc0;                                  \
      facc& kd = (W & 1) ? ka2 : ka0;                                          \
      _Pragma("unroll")                                                        \
      for (int r = 0; r < 16; ++r)                                             \
        kd[r] = fmaf(xv, cc0[r] + cc1[r] + cc2[r], kd[r]);                     \
    } else if (W == 4) {                                                       \
      _Pragma("unroll")                                                        \
      for (int r = 0; r < 16; ++r) {                                           \
        const float s = cc0[r] + cc1[r] + cc2[r];                              \
        ka1[r] = fmaf(xkc1, s, ka1[r]);                                        \
        ka3[r] = fmaf(xkc3, s, ka3[r]);                                        \
      }                                                                        \
    } else {                                                                   \
      _Pragma("unroll")                                                        \
      for (int r = 0; r < 16; ++r) {                                           \
        const float s = cc0[r] + cc1[r] + cc2[r];                              \
        ka1[r] = fmaf(xkc3, s, ka1[r]);                                        \
        ka3[r] = fmaf(-xkc1, s, ka3[r]);                                       \
      }                                                                        \
    }                                                                          \
  }

  // main: 7 x 12 phases (tiles 0..83); buffer idx (II)%4 and W=(II)%6 static
  for (int ot = 0; ot < 7; ++ot) {
    const int base = ot * 12;
    PHASE(base + 0,  0,  true, "4", true)
    PHASE(base + 1,  1,  true, "4", true)
    PHASE(base + 2,  2,  true, "4", true)
    PHASE(base + 3,  3,  true, "4", true)
    PHASE(base + 4,  4,  true, "4", true)
    PHASE(base + 5,  5,  true, "4", true)
    PHASE(base + 6,  6,  true, "4", true)
    PHASE(base + 7,  7,  true, "4", true)
    PHASE(base + 8,  8,  true, "4", true)
    PHASE(base + 9,  9,  true, "4", true)
    PHASE(base + 10, 10, true, "4", true)
    PHASE(base + 11, 11, true, "4", true)
  }
  // tail: tiles 84..95 (stage while target<=95; ramp vmcnt down 4->2->0)
  PHASE(84, 0,  true,  "4", true)
  PHASE(85, 1,  true,  "4", true)
  PHASE(86, 2,  true,  "4", true)
  PHASE(87, 3,  true,  "4", true)
  PHASE(88, 4,  true,  "4", true)
  PHASE(89, 5,  true,  "4", true)
  PHASE(90, 6,  true,  "4", true)
  PHASE(91, 7,  true,  "4", true)
  PHASE(92, 8,  true,  "4", true)
  PHASE(93, 9,  false, "2", true)
  PHASE(94, 10, false, "0", true)
  PHASE(95, 11, false, "0", false)
#undef PHASE

  // ---- q via MFMA (same C layout as ka), full z per wave, direct store
  bfrag xqh[4], xql[4];
#pragma unroll
  for (int a = 0; a < 4; ++a) {
    float tmp[8];
    *(float4*)&tmp[0] = *(const float4*)(x_q + (size_t)e * 64 + a * 16 + half * 8);
    *(float4*)&tmp[4] = *(const float4*)(x_q + (size_t)e * 64 + a * 16 + half * 8 + 4);
    cvt8(tmp, xqh[a], xql[a]);
  }
  float zp0 = 0.f, zp1 = 0.f, zp2 = 0.f, zp3 = 0.f;
  const int QA1[4] = {0, 1, 0, 3}, QS1[4] = {0, 4, 1, 4};
  const int QA2[4] = {2, 3, 2, 1}, QS2[4] = {2, 5, 3, 6};  // slot 6 = -Wq[5]
#pragma unroll
  for (int m = 0; m < 4; ++m) {
    facc qa = {0.f};
#pragma unroll
    for (int tm = 0; tm < 2; ++tm) {
      const int a = tm ? QA2[m] : QA1[m];
      const int sl = tm ? QS2[m] : QS1[m];
      bfrag wh, wl;
      *(uint4*)&wh = *(const uint4*)(fragWq + sl * 1024 + lane * 8);
      *(uint4*)&wl = *(const uint4*)(fragWq + sl * 1024 + 512 + lane * 8);
      qa = __builtin_amdgcn_mfma_f32_32x32x16_bf16(wh, xqh[a], qa, 0, 0, 0);
      qa = __builtin_amdgcn_mfma_f32_32x32x16_bf16(wh, xql[a], qa, 0, 0, 0);
      qa = __builtin_amdgcn_mfma_f32_32x32x16_bf16(wl, xqh[a], qa, 0, 0, 0);
    }
    const facc& km = (m == 0) ? ka0 : (m == 1) ? ka1 : (m == 2) ? ka2 : ka3;
#pragma unroll
    for (int r = 0; r < 16; ++r) {
      const float v = qa[r] * km[r];
      if (r < 4) zp0 += v;
      else if (r < 8) zp1 += v;
      else if (r < 12) zp2 += v;
      else zp3 += v;
    }
  }
  zp0 += __shfl_xor(zp0, 32);
  zp1 += __shfl_xor(zp1, 32);
  zp2 += __shfl_xor(zp2, 32);
  zp3 += __shfl_xor(zp3, 32);
  if (half == 0) {
    float4 v = {zp0 * SCALE, zp1 * SCALE, zp2 * SCALE, zp3 * SCALE};
    *(float4*)&z[(size_t)e * 4] = v;
  }
}

// ---------------------------------------------------------------------------
__global__ __launch_bounds__(256) void softmax_kernel(
    const float* __restrict__ z, const int* __restrict__ offs,
    float* __restrict__ out)
{
  const int node = blockIdx.x * 4 + (threadIdx.x >> 6);
  const int lane = threadIdx.x & 63;
  const int start = offs[node], end = offs[node + 1];
  if (start >= end) return;
  const int h = lane & 3, eo = lane >> 2;
  float m = -INFINITY;
  for (int e = start + eo; e < end; e += 16) m = fmaxf(m, z[(size_t)e * 4 + h]);
#pragma unroll
  for (int s = 4; s < 64; s <<= 1) m = fmaxf(m, __shfl_xor(m, s));
  float sum = 0.f;
  for (int e = start + eo; e < end; e += 16) sum += __expf(z[(size_t)e * 4 + h] - m);
#pragma unroll
  for (int s = 4; s < 64; s <<= 1) sum += __shfl_xor(sum, s);
  const float inv = 1.f / sum;
  for (int e = start + eo; e < end; e += 16)
    out[(size_t)e * 4 + h] = __expf(z[(size_t)e * 4 + h] - m) * inv;
}

extern "C" void kernel_launch(void* const* d_in, const int* in_sizes, int n_in,
                              void* d_out, int out_size, void* d_ws, size_t ws_size,
                              hipStream_t stream) {
  const float* x_q = (const float*)d_in[0];
  const float* x_k = (const float*)d_in[1];
  const float* emb = (const float*)d_in[2];
  const int* index = (const int*)d_in[3];
  const float* W_q = (const float*)d_in[4];
  const float* W_p = (const float*)d_in[5];
  float* out = (float*)d_out;

  char* ws = (char*)d_ws;
  float* z = (float*)ws;                                                    // 524288 B
  int* offs = (int*)(ws + 524288);                                          // 16388 B (pad 32 KB)
  unsigned short* fragWp = (unsigned short*)(ws + 524288 + 32768);          // 786432 B
  unsigned short* fragWq = (unsigned short*)(ws + 524288 + 32768 + 786432); // 14336 B

  prep_kernel<<<231, 256, 0, stream>>>(W_p, W_q, index, fragWp, fragWq, offs);
  main_kernel<<<256, 256, 0, stream>>>(x_q, x_k, emb, fragWp, fragWq, z);
  softmax_kernel<<<1024, 256, 0, stream>>>(z, offs, out);
}

// Round 5
// 158.037 us; speedup vs baseline: 1.0378x; 1.0378x over previous
//
#include <hip/hip_runtime.h>
#include <math.h>

#define E_TOTAL 32768
#define NUM_NODES 4096
#define SCALE 0.70710678118654752f

typedef __attribute__((ext_vector_type(8))) short bfrag;
typedef __attribute__((ext_vector_type(16))) float facc;

__device__ inline unsigned short f2bf(float f) {
  unsigned int u = __float_as_uint(f);
  unsigned int r = (u + 0x7FFFu + ((u >> 16) & 1u)) >> 16;
  return (unsigned short)r;
}
__device__ inline float bf2f(unsigned short s) {
  return __uint_as_float(((unsigned int)s) << 16);
}
__device__ inline void cvt8(const float* v, bfrag& hi, bfrag& lo) {
#pragma unroll
  for (int i = 0; i < 8; ++i) {
    unsigned short h = f2bf(v[i]);
    hi[i] = (short)h;
    lo[i] = (short)f2bf(v[i] - bf2f(h));
  }
}

// async global->LDS, 16 B per lane, wave-uniform LDS base + lane*16
__device__ inline void stage16(const void* g, void* l) {
  __builtin_amdgcn_global_load_lds(
      (const __attribute__((address_space(1))) unsigned int*)g,
      (__attribute__((address_space(3))) unsigned int*)l, 16, 0, 0);
}

// ---------------------------------------------------------------------------
// Combined prep: blocks 0..95 W_p frags, 96..102 W_q frags, 103..230 offsets
// frag layout per n-tile nt=c*6+w: [ks(4)][hl(2)][lane(64)][j(8)] bf16 (8 KB)
//   element = W_p[d][w*512 + c*32 + (lane&31)], d = ks*16 + (lane>>5)*8 + j
// ---------------------------------------------------------------------------
__global__ __launch_bounds__(256) void prep_kernel(
    const float* __restrict__ Wp, const float* __restrict__ Wq,
    const int* __restrict__ index,
    unsigned short* __restrict__ fragWp, unsigned short* __restrict__ fragWq,
    int* __restrict__ offs)
{
  const int b = blockIdx.x, t = threadIdx.x;
  if (b < 96) {
    __shared__ unsigned short lds[4096];
    const int c = b / 6, w = b - c * 6;
    const int colbase = w * 512 + c * 32;
    const int cl = t & 31, dg = t >> 5;
#pragma unroll
    for (int i = 0; i < 8; ++i) {
      const int d = dg * 8 + i;
      const float v = Wp[(size_t)d * 3072 + colbase + cl];
      const unsigned short hi = f2bf(v);
      const unsigned short lo = f2bf(v - bf2f(hi));
      const int ks = d >> 4;
      const int lane = ((d >> 3) & 1) * 32 + cl;
      const int j = d & 7;
      lds[(ks * 2 + 0) * 512 + lane * 8 + j] = hi;
      lds[(ks * 2 + 1) * 512 + lane * 8 + j] = lo;
    }
    __syncthreads();
    unsigned short* dst = fragWp + (size_t)b * 4096;
    ((uint4*)dst)[t] = ((const uint4*)lds)[t];
    ((uint4*)dst)[t + 256] = ((const uint4*)lds)[t + 256];
  } else if (b < 103) {
    const int slot = b - 96;
    const int w = (slot == 6) ? 5 : slot;
    const float sgn = (slot == 6) ? -1.f : 1.f;
    for (int tt = t; tt < 512; tt += 256) {
      const int lane = tt >> 3, j = tt & 7;
      const int o = lane & 31, c = (lane >> 5) * 8 + j;
      const float v = sgn * Wq[(size_t)(w * 16 + c) * 32 + o];
      const unsigned short hi = f2bf(v);
      const unsigned short lo = f2bf(v - bf2f(hi));
      fragWq[slot * 1024 + lane * 8 + j] = hi;
      fragWq[slot * 1024 + 512 + lane * 8 + j] = lo;
    }
  } else {
    const int tg = (b - 103) * 256 + t;
    if (tg >= E_TOTAL) return;
    const int cur = index[tg];
    const int prev = (tg == 0) ? -1 : index[tg - 1];
    for (int n = prev + 1; n <= cur; ++n) offs[n] = tg;
    if (tg == E_TOTAL - 1)
      for (int n = cur + 1; n <= NUM_NODES; ++n) offs[n] = E_TOTAL;
  }
}

// ---------------------------------------------------------------------------
// Main: 256 blocks (1/CU), 4 waves, 128 edges/block, 32 edges/wave.
// LDS-staged W stream, counted-vmcnt pipeline (T3+T4), DEPTH=4 ring, one raw
// s_barrier per tile, never vmcnt(0) in steady state. Phase k:
//   vmcnt(4)+lgkmcnt(0); s_barrier   (tile k staged block-wide; k-1 reads retired)
//   stage(k+3)->buf[(k-1)%4]         (safe overwrite, 6 loads in flight max)
//   ds_read tile k -> LOCAL fh/fl (no cross-phase reg dbuf -> no spill, R4 fix)
//   12x MFMA + so2 contraction       (compiler interleaves via lgkmcnt)
// Each wave's ka is COMPLETE (all 96 tiles) -> no cross-wave reduce.
// ---------------------------------------------------------------------------
__global__ __launch_bounds__(256, 1) void main_kernel(
    const float* __restrict__ x_q, const float* __restrict__ x_k,
    const float* __restrict__ emb,
    const unsigned short* __restrict__ fragWp,
    const unsigned short* __restrict__ fragWq,
    float* __restrict__ z)
{
  __shared__ float xk_t[64][129];                       // 33 KB, padded
  __shared__ alignas(16) unsigned short wbuf[4][4096];  // 4 x 8 KB tile ring

  const int t = threadIdx.x;
  const int lane = t & 63, wv = t >> 6;
  const int col = lane & 31, half = lane >> 5;
  const int eb = blockIdx.x * 128;
  const int el = wv * 32 + col;
  const int e = eb + el;

  // issue stages for tiles 0,1,2 ASAP (drained by the prologue syncthreads)
#pragma unroll
  for (int pt = 0; pt < 3; ++pt) {
    const char* tb = (const char*)fragWp + (size_t)pt * 8192;
    char* db = (char*)&wbuf[pt][0];
    stage16(tb + (wv * 2 + 0) * 1024 + lane * 16, db + (wv * 2 + 0) * 1024);
    stage16(tb + (wv * 2 + 1) * 1024 + lane * 16, db + (wv * 2 + 1) * 1024);
  }

  // stage x_k transposed: thread t -> edge t&127, d-half (t>>7)*32
  {
    const int er = t & 127, dh = (t >> 7) * 32;
    const float* src = x_k + (size_t)(eb + er) * 64 + dh;
#pragma unroll
    for (int i = 0; i < 8; ++i) {
      float4 v = *(const float4*)(src + i * 4);
      xk_t[dh + i * 4 + 0][er] = v.x;
      xk_t[dh + i * 4 + 1][er] = v.y;
      xk_t[dh + i * 4 + 2][er] = v.z;
      xk_t[dh + i * 4 + 3][er] = v.w;
    }
  }

  // emb B-fragments hi/lo for this wave's 32 edges: B[k=d][col=e]
  bfrag ebh[4], ebl[4];
#pragma unroll
  for (int ks = 0; ks < 4; ++ks) {
    float tmp[8];
    *(float4*)&tmp[0] = *(const float4*)(emb + (size_t)e * 64 + ks * 16 + half * 8);
    *(float4*)&tmp[4] = *(const float4*)(emb + (size_t)e * 64 + ks * 16 + half * 8 + 4);
    cvt8(tmp, ebh[ks], ebl[ks]);
  }

  facc ka0 = {0}, ka1 = {0}, ka2 = {0}, ka3 = {0};

  __syncthreads();  // ONE full drain: xk_t + tiles 0-2 staged + emb loads done

  float xkc0 = 0.f, xkc1 = 0.f, xkc2 = 0.f, xkc3 = 0.f;

#define PHASE(IT, II, DO_STAGE, VMN_STR)                                       \
  {                                                                            \
    asm volatile("s_waitcnt vmcnt(" VMN_STR ") lgkmcnt(0)" ::: "memory");      \
    __builtin_amdgcn_s_barrier();                                              \
    asm volatile("" ::: "memory");                                             \
    if (DO_STAGE) {                                                            \
      const char* tb = (const char*)fragWp + (size_t)((IT) + 3) * 8192;        \
      char* db = (char*)&wbuf[((II) + 3) & 3][0];                              \
      stage16(tb + (wv * 2 + 0) * 1024 + lane * 16, db + (wv * 2 + 0) * 1024); \
      stage16(tb + (wv * 2 + 1) * 1024 + lane * 16, db + (wv * 2 + 1) * 1024); \
    }                                                                          \
    if (((II) % 6) == 0) {                                                     \
      const int c16 = (IT) / 6;                                                \
      xkc0 = xk_t[c16][el];      xkc1 = xk_t[16 + c16][el];                    \
      xkc2 = xk_t[32 + c16][el]; xkc3 = xk_t[48 + c16][el];                    \
    }                                                                          \
    const unsigned short* wb = &wbuf[(II) & 3][0] + lane * 8;                  \
    bfrag fh[4], fl[4];                                                        \
    _Pragma("unroll")                                                          \
    for (int ks = 0; ks < 4; ++ks) {                                           \
      *(uint4*)&fh[ks] = *(const uint4*)(wb + ks * 1024);                      \
      *(uint4*)&fl[ks] = *(const uint4*)(wb + ks * 1024 + 512);                \
    }                                                                          \
    facc cc0 = {0.f}, cc1 = {0.f}, cc2 = {0.f};                                \
    _Pragma("unroll")                                                          \
    for (int ks = 0; ks < 4; ++ks) {                                           \
      cc0 = __builtin_amdgcn_mfma_f32_32x32x16_bf16(fh[ks], ebh[ks], cc0, 0, 0, 0); \
      cc1 = __builtin_amdgcn_mfma_f32_32x32x16_bf16(fh[ks], ebl[ks], cc1, 0, 0, 0); \
      cc2 = __builtin_amdgcn_mfma_f32_32x32x16_bf16(fl[ks], ebh[ks], cc2, 0, 0, 0); \
    }                                                                          \
    const int W = (II) % 6;                                                    \
    if (W < 4) {                                                               \
      const float xv = (W & 2) ? xkc2 : xkc0;                                  \
      facc& kd = (W & 1) ? ka2 : ka0;                                          \
      _Pragma("unroll")                                                        \
      for (int r = 0; r < 16; ++r)                                             \
        kd[r] = fmaf(xv, cc0[r] + cc1[r] + cc2[r], kd[r]);                     \
    } else if (W == 4) {                                                       \
      _Pragma("unroll")                                                        \
      for (int r = 0; r < 16; ++r) {                                           \
        const float s = cc0[r] + cc1[r] + cc2[r];                              \
        ka1[r] = fmaf(xkc1, s, ka1[r]);                                        \
        ka3[r] = fmaf(xkc3, s, ka3[r]);                                        \
      }                                                                        \
    } else {                                                                   \
      _Pragma("unroll")                                                        \
      for (int r = 0; r < 16; ++r) {                                           \
        const float s = cc0[r] + cc1[r] + cc2[r];                              \
        ka1[r] = fmaf(xkc3, s, ka1[r]);                                        \
        ka3[r] = fmaf(-xkc1, s, ka3[r]);                                       \
      }                                                                        \
    }                                                                          \
  }

  // main: 7 x 12 phases (tiles 0..83); (II)&3 and (II)%6 static (12%4=12%6... both cycle cleanly)
  for (int ot = 0; ot < 7; ++ot) {
    const int base = ot * 12;
    PHASE(base + 0,  0,  true, "4")
    PHASE(base + 1,  1,  true, "4")
    PHASE(base + 2,  2,  true, "4")
    PHASE(base + 3,  3,  true, "4")
    PHASE(base + 4,  4,  true, "4")
    PHASE(base + 5,  5,  true, "4")
    PHASE(base + 6,  6,  true, "4")
    PHASE(base + 7,  7,  true, "4")
    PHASE(base + 8,  8,  true, "4")
    PHASE(base + 9,  9,  true, "4")
    PHASE(base + 10, 10, true, "4")
    PHASE(base + 11, 11, true, "4")
  }
  // tail: tiles 84..95; stages end at phase 92 (tile 95); vmcnt ramps 4->2->0
  PHASE(84, 0,  true,  "4")
  PHASE(85, 1,  true,  "4")
  PHASE(86, 2,  true,  "4")
  PHASE(87, 3,  true,  "4")
  PHASE(88, 4,  true,  "4")
  PHASE(89, 5,  true,  "4")
  PHASE(90, 6,  true,  "4")
  PHASE(91, 7,  true,  "4")
  PHASE(92, 8,  true,  "4")
  PHASE(93, 9,  false, "4")
  PHASE(94, 10, false, "2")
  PHASE(95, 11, false, "0")
#undef PHASE

  // ---- q via MFMA (same C layout as ka), full z per wave, direct store
  bfrag xqh[4], xql[4];
#pragma unroll
  for (int a = 0; a < 4; ++a) {
    float tmp[8];
    *(float4*)&tmp[0] = *(const float4*)(x_q + (size_t)e * 64 + a * 16 + half * 8);
    *(float4*)&tmp[4] = *(const float4*)(x_q + (size_t)e * 64 + a * 16 + half * 8 + 4);
    cvt8(tmp, xqh[a], xql[a]);
  }
  float zp0 = 0.f, zp1 = 0.f, zp2 = 0.f, zp3 = 0.f;
  const int QA1[4] = {0, 1, 0, 3}, QS1[4] = {0, 4, 1, 4};
  const int QA2[4] = {2, 3, 2, 1}, QS2[4] = {2, 5, 3, 6};  // slot 6 = -Wq[5]
#pragma unroll
  for (int m = 0; m < 4; ++m) {
    facc qa = {0.f};
#pragma unroll
    for (int tm = 0; tm < 2; ++tm) {
      const int a = tm ? QA2[m] : QA1[m];
      const int sl = tm ? QS2[m] : QS1[m];
      bfrag wh, wl;
      *(uint4*)&wh = *(const uint4*)(fragWq + sl * 1024 + lane * 8);
      *(uint4*)&wl = *(const uint4*)(fragWq + sl * 1024 + 512 + lane * 8);
      qa = __builtin_amdgcn_mfma_f32_32x32x16_bf16(wh, xqh[a], qa, 0, 0, 0);
      qa = __builtin_amdgcn_mfma_f32_32x32x16_bf16(wh, xql[a], qa, 0, 0, 0);
      qa = __builtin_amdgcn_mfma_f32_32x32x16_bf16(wl, xqh[a], qa, 0, 0, 0);
    }
    const facc& km = (m == 0) ? ka0 : (m == 1) ? ka1 : (m == 2) ? ka2 : ka3;
#pragma unroll
    for (int r = 0; r < 16; ++r) {
      const float v = qa[r] * km[r];
      if (r < 4) zp0 += v;
      else if (r < 8) zp1 += v;
      else if (r < 12) zp2 += v;
      else zp3 += v;
    }
  }
  zp0 += __shfl_xor(zp0, 32);
  zp1 += __shfl_xor(zp1, 32);
  zp2 += __shfl_xor(zp2, 32);
  zp3 += __shfl_xor(zp3, 32);
  if (half == 0) {
    float4 v = {zp0 * SCALE, zp1 * SCALE, zp2 * SCALE, zp3 * SCALE};
    *(float4*)&z[(size_t)e * 4] = v;
  }
}

// ---------------------------------------------------------------------------
__global__ __launch_bounds__(256) void softmax_kernel(
    const float* __restrict__ z, const int* __restrict__ offs,
    float* __restrict__ out)
{
  const int node = blockIdx.x * 4 + (threadIdx.x >> 6);
  const int lane = threadIdx.x & 63;
  const int start = offs[node], end = offs[node + 1];
  if (start >= end) return;
  const int h = lane & 3, eo = lane >> 2;
  float m = -INFINITY;
  for (int e = start + eo; e < end; e += 16) m = fmaxf(m, z[(size_t)e * 4 + h]);
#pragma unroll
  for (int s = 4; s < 64; s <<= 1) m = fmaxf(m, __shfl_xor(m, s));
  float sum = 0.f;
  for (int e = start + eo; e < end; e += 16) sum += __expf(z[(size_t)e * 4 + h] - m);
#pragma unroll
  for (int s = 4; s < 64; s <<= 1) sum += __shfl_xor(sum, s);
  const float inv = 1.f / sum;
  for (int e = start + eo; e < end; e += 16)
    out[(size_t)e * 4 + h] = __expf(z[(size_t)e * 4 + h] - m) * inv;
}

extern "C" void kernel_launch(void* const* d_in, const int* in_sizes, int n_in,
                              void* d_out, int out_size, void* d_ws, size_t ws_size,
                              hipStream_t stream) {
  const float* x_q = (const float*)d_in[0];
  const float* x_k = (const float*)d_in[1];
  const float* emb = (const float*)d_in[2];
  const int* index = (const int*)d_in[3];
  const float* W_q = (const float*)d_in[4];
  const float* W_p = (const float*)d_in[5];
  float* out = (float*)d_out;

  char* ws = (char*)d_ws;
  float* z = (float*)ws;                                                    // 524288 B
  int* offs = (int*)(ws + 524288);                                          // 16388 B (pad 32 KB)
  unsigned short* fragWp = (unsigned short*)(ws + 524288 + 32768);          // 786432 B
  unsigned short* fragWq = (unsigned short*)(ws + 524288 + 32768 + 786432); // 14336 B

  prep_kernel<<<231, 256, 0, stream>>>(W_p, W_q, index, fragWp, fragWq, offs);
  main_kernel<<<256, 256, 0, stream>>>(x_q, x_k, emb, fragWp, fragWq, z);
  softmax_kernel<<<1024, 256, 0, stream>>>(z, offs, out);
}

// Round 6
// 138.130 us; speedup vs baseline: 1.1873x; 1.1441x over previous
//
#include <hip/hip_runtime.h>
#include <math.h>

#define E_TOTAL 32768
#define NUM_NODES 4096
#define SCALE 0.70710678118654752f

typedef __attribute__((ext_vector_type(8))) short bfrag;
typedef __attribute__((ext_vector_type(16))) float facc;

__device__ inline unsigned short f2bf(float f) {
  unsigned int u = __float_as_uint(f);
  unsigned int r = (u + 0x7FFFu + ((u >> 16) & 1u)) >> 16;
  return (unsigned short)r;
}
__device__ inline float bf2f(unsigned short s) {
  return __uint_as_float(((unsigned int)s) << 16);
}
__device__ inline void cvt8(const float* v, bfrag& hi, bfrag& lo) {
#pragma unroll
  for (int i = 0; i < 8; ++i) {
    unsigned short h = f2bf(v[i]);
    hi[i] = (short)h;
    lo[i] = (short)f2bf(v[i] - bf2f(h));
  }
}

// async global->LDS, 16 B per lane, wave-uniform LDS base + lane*16
__device__ inline void stage16(const void* g, void* l) {
  __builtin_amdgcn_global_load_lds(
      (const __attribute__((address_space(1))) unsigned int*)g,
      (__attribute__((address_space(3))) unsigned int*)l, 16, 0, 0);
}

// ---------------------------------------------------------------------------
// Combined prep: blocks 0..95 W_p frags, 96..102 W_q frags, 103..230 offsets
// frag layout per n-tile nt=c*6+w: [ks(4)][hl(2)][lane(64)][j(8)] bf16 (8 KB)
//   element = W_p[d][w*512 + c*32 + (lane&31)], d = ks*16 + (lane>>5)*8 + j
// ---------------------------------------------------------------------------
__global__ __launch_bounds__(256) void prep_kernel(
    const float* __restrict__ Wp, const float* __restrict__ Wq,
    const int* __restrict__ index,
    unsigned short* __restrict__ fragWp, unsigned short* __restrict__ fragWq,
    int* __restrict__ offs)
{
  const int b = blockIdx.x, t = threadIdx.x;
  if (b < 96) {
    __shared__ unsigned short lds[4096];
    const int c = b / 6, w = b - c * 6;
    const int colbase = w * 512 + c * 32;
    const int cl = t & 31, dg = t >> 5;
#pragma unroll
    for (int i = 0; i < 8; ++i) {
      const int d = dg * 8 + i;
      const float v = Wp[(size_t)d * 3072 + colbase + cl];
      const unsigned short hi = f2bf(v);
      const unsigned short lo = f2bf(v - bf2f(hi));
      const int ks = d >> 4;
      const int lane = ((d >> 3) & 1) * 32 + cl;
      const int j = d & 7;
      lds[(ks * 2 + 0) * 512 + lane * 8 + j] = hi;
      lds[(ks * 2 + 1) * 512 + lane * 8 + j] = lo;
    }
    __syncthreads();
    unsigned short* dst = fragWp + (size_t)b * 4096;
    ((uint4*)dst)[t] = ((const uint4*)lds)[t];
    ((uint4*)dst)[t + 256] = ((const uint4*)lds)[t + 256];
  } else if (b < 103) {
    const int slot = b - 96;
    const int w = (slot == 6) ? 5 : slot;
    const float sgn = (slot == 6) ? -1.f : 1.f;
    for (int tt = t; tt < 512; tt += 256) {
      const int lane = tt >> 3, j = tt & 7;
      const int o = lane & 31, c = (lane >> 5) * 8 + j;
      const float v = sgn * Wq[(size_t)(w * 16 + c) * 32 + o];
      const unsigned short hi = f2bf(v);
      const unsigned short lo = f2bf(v - bf2f(hi));
      fragWq[slot * 1024 + lane * 8 + j] = hi;
      fragWq[slot * 1024 + 512 + lane * 8 + j] = lo;
    }
  } else {
    const int tg = (b - 103) * 256 + t;
    if (tg >= E_TOTAL) return;
    const int cur = index[tg];
    const int prev = (tg == 0) ? -1 : index[tg - 1];
    for (int n = prev + 1; n <= cur; ++n) offs[n] = tg;
    if (tg == E_TOTAL - 1)
      for (int n = cur + 1; n <= NUM_NODES; ++n) offs[n] = E_TOTAL;
  }
}

// ---------------------------------------------------------------------------
// Main: 256 blocks (1/CU), 4 waves, 128 edges/block, 32 edges/wave.
// LDS-staged W stream, counted-vmcnt pipeline, DEPTH=4 ring, one raw
// s_barrier per tile, never vmcnt(0) in steady state.
// Spill fixes (R5 -> R6): 2 MFMA chains not 3 (acc 48->32 regs); per-ks
// fragment loads (f 16->8 regs); sched_barrier(0) at phase end stops the
// scheduler stretching cc/frag live ranges across phases (R5's spill cause).
// ---------------------------------------------------------------------------
__global__ __launch_bounds__(256, 1) void main_kernel(
    const float* __restrict__ x_q, const float* __restrict__ x_k,
    const float* __restrict__ emb,
    const unsigned short* __restrict__ fragWp,
    const unsigned short* __restrict__ fragWq,
    float* __restrict__ z)
{
  __shared__ float xk_t[64][129];                       // 33 KB, padded
  __shared__ alignas(16) unsigned short wbuf[4][4096];  // 4 x 8 KB tile ring

  const int t = threadIdx.x;
  const int lane = t & 63, wv = t >> 6;
  const int col = lane & 31, half = lane >> 5;
  const int eb = blockIdx.x * 128;
  const int el = wv * 32 + col;
  const int e = eb + el;

  // issue stages for tiles 0,1,2 ASAP (drained by the prologue syncthreads)
#pragma unroll
  for (int pt = 0; pt < 3; ++pt) {
    const char* tb = (const char*)fragWp + (size_t)pt * 8192;
    char* db = (char*)&wbuf[pt][0];
    stage16(tb + (wv * 2 + 0) * 1024 + lane * 16, db + (wv * 2 + 0) * 1024);
    stage16(tb + (wv * 2 + 1) * 1024 + lane * 16, db + (wv * 2 + 1) * 1024);
  }

  // stage x_k transposed: thread t -> edge t&127, d-half (t>>7)*32
  {
    const int er = t & 127, dh = (t >> 7) * 32;
    const float* src = x_k + (size_t)(eb + er) * 64 + dh;
#pragma unroll
    for (int i = 0; i < 8; ++i) {
      float4 v = *(const float4*)(src + i * 4);
      xk_t[dh + i * 4 + 0][er] = v.x;
      xk_t[dh + i * 4 + 1][er] = v.y;
      xk_t[dh + i * 4 + 2][er] = v.z;
      xk_t[dh + i * 4 + 3][er] = v.w;
    }
  }

  // emb B-fragments hi/lo for this wave's 32 edges: B[k=d][col=e]
  bfrag ebh[4], ebl[4];
#pragma unroll
  for (int ks = 0; ks < 4; ++ks) {
    float tmp[8];
    *(float4*)&tmp[0] = *(const float4*)(emb + (size_t)e * 64 + ks * 16 + half * 8);
    *(float4*)&tmp[4] = *(const float4*)(emb + (size_t)e * 64 + ks * 16 + half * 8 + 4);
    cvt8(tmp, ebh[ks], ebl[ks]);
  }

  facc ka0 = {0}, ka1 = {0}, ka2 = {0}, ka3 = {0};

  __syncthreads();  // ONE full drain: xk_t + tiles 0-2 staged + emb loads done

  float xkc0 = 0.f, xkc1 = 0.f, xkc2 = 0.f, xkc3 = 0.f;

#define PHASE(IT, II, DO_STAGE, VMN_STR)                                       \
  {                                                                            \
    asm volatile("s_waitcnt vmcnt(" VMN_STR ") lgkmcnt(0)" ::: "memory");      \
    __builtin_amdgcn_s_barrier();                                              \
    asm volatile("" ::: "memory");                                             \
    if (DO_STAGE) {                                                            \
      const char* tb = (const char*)fragWp + (size_t)((IT) + 3) * 8192;        \
      char* db = (char*)&wbuf[((II) + 3) & 3][0];                              \
      stage16(tb + (wv * 2 + 0) * 1024 + lane * 16, db + (wv * 2 + 0) * 1024); \
      stage16(tb + (wv * 2 + 1) * 1024 + lane * 16, db + (wv * 2 + 1) * 1024); \
    }                                                                          \
    if (((II) % 6) == 0) {                                                     \
      const int c16 = (IT) / 6;                                                \
      xkc0 = xk_t[c16][el];      xkc1 = xk_t[16 + c16][el];                    \
      xkc2 = xk_t[32 + c16][el]; xkc3 = xk_t[48 + c16][el];                    \
    }                                                                          \
    const unsigned short* wb = &wbuf[(II) & 3][0] + lane * 8;                  \
    facc cc0 = {0.f}, cc1 = {0.f};                                             \
    _Pragma("unroll")                                                          \
    for (int ks = 0; ks < 4; ++ks) {                                           \
      bfrag fh, fl;                                                            \
      *(uint4*)&fh = *(const uint4*)(wb + ks * 1024);                          \
      *(uint4*)&fl = *(const uint4*)(wb + ks * 1024 + 512);                    \
      cc0 = __builtin_amdgcn_mfma_f32_32x32x16_bf16(fh, ebh[ks], cc0, 0, 0, 0);\
      cc1 = __builtin_amdgcn_mfma_f32_32x32x16_bf16(fh, ebl[ks], cc1, 0, 0, 0);\
      cc1 = __builtin_amdgcn_mfma_f32_32x32x16_bf16(fl, ebh[ks], cc1, 0, 0, 0);\
    }                                                                          \
    const int W = (II) % 6;                                                    \
    if (W < 4) {                                                               \
      const float xv = (W & 2) ? xkc2 : xkc0;                                  \
      facc& kd = (W & 1) ? ka2 : ka0;                                          \
      _Pragma("unroll")                                                        \
      for (int r = 0; r < 16; ++r)                                             \
        kd[r] = fmaf(xv, cc0[r] + cc1[r], kd[r]);                              \
    } else if (W == 4) {                                                       \
      _Pragma("unroll")                                                        \
      for (int r = 0; r < 16; ++r) {                                           \
        const float s = cc0[r] + cc1[r];                                       \
        ka1[r] = fmaf(xkc1, s, ka1[r]);                                        \
        ka3[r] = fmaf(xkc3, s, ka3[r]);                                        \
      }                                                                        \
    } else {                                                                   \
      _Pragma("unroll")                                                        \
      for (int r = 0; r < 16; ++r) {                                           \
        const float s = cc0[r] + cc1[r];                                       \
        ka1[r] = fmaf(xkc3, s, ka1[r]);                                        \
        ka3[r] = fmaf(-xkc1, s, ka3[r]);                                       \
      }                                                                        \
    }                                                                          \
    __builtin_amdgcn_sched_barrier(0);                                         \
  }

  // main: 7 x 12 phases (tiles 0..83); (II)&3 and (II)%6 both cycle at 12
  for (int ot = 0; ot < 7; ++ot) {
    const int base = ot * 12;
    PHASE(base + 0,  0,  true, "4")
    PHASE(base + 1,  1,  true, "4")
    PHASE(base + 2,  2,  true, "4")
    PHASE(base + 3,  3,  true, "4")
    PHASE(base + 4,  4,  true, "4")
    PHASE(base + 5,  5,  true, "4")
    PHASE(base + 6,  6,  true, "4")
    PHASE(base + 7,  7,  true, "4")
    PHASE(base + 8,  8,  true, "4")
    PHASE(base + 9,  9,  true, "4")
    PHASE(base + 10, 10, true, "4")
    PHASE(base + 11, 11, true, "4")
  }
  // tail: tiles 84..95; stages end at phase 92 (tile 95); vmcnt ramps 4->2->0
  PHASE(84, 0,  true,  "4")
  PHASE(85, 1,  true,  "4")
  PHASE(86, 2,  true,  "4")
  PHASE(87, 3,  true,  "4")
  PHASE(88, 4,  true,  "4")
  PHASE(89, 5,  true,  "4")
  PHASE(90, 6,  true,  "4")
  PHASE(91, 7,  true,  "4")
  PHASE(92, 8,  true,  "4")
  PHASE(93, 9,  false, "4")
  PHASE(94, 10, false, "2")
  PHASE(95, 11, false, "0")
#undef PHASE

  // ---- q via MFMA (same C layout as ka), full z per wave, direct store
  bfrag xqh[4], xql[4];
#pragma unroll
  for (int a = 0; a < 4; ++a) {
    float tmp[8];
    *(float4*)&tmp[0] = *(const float4*)(x_q + (size_t)e * 64 + a * 16 + half * 8);
    *(float4*)&tmp[4] = *(const float4*)(x_q + (size_t)e * 64 + a * 16 + half * 8 + 4);
    cvt8(tmp, xqh[a], xql[a]);
  }
  float zp0 = 0.f, zp1 = 0.f, zp2 = 0.f, zp3 = 0.f;
  const int QA1[4] = {0, 1, 0, 3}, QS1[4] = {0, 4, 1, 4};
  const int QA2[4] = {2, 3, 2, 1}, QS2[4] = {2, 5, 3, 6};  // slot 6 = -Wq[5]
#pragma unroll
  for (int m = 0; m < 4; ++m) {
    facc qa = {0.f};
#pragma unroll
    for (int tm = 0; tm < 2; ++tm) {
      const int a = tm ? QA2[m] : QA1[m];
      const int sl = tm ? QS2[m] : QS1[m];
      bfrag wh, wl;
      *(uint4*)&wh = *(const uint4*)(fragWq + sl * 1024 + lane * 8);
      *(uint4*)&wl = *(const uint4*)(fragWq + sl * 1024 + 512 + lane * 8);
      qa = __builtin_amdgcn_mfma_f32_32x32x16_bf16(wh, xqh[a], qa, 0, 0, 0);
      qa = __builtin_amdgcn_mfma_f32_32x32x16_bf16(wh, xql[a], qa, 0, 0, 0);
      qa = __builtin_amdgcn_mfma_f32_32x32x16_bf16(wl, xqh[a], qa, 0, 0, 0);
    }
    const facc& km = (m == 0) ? ka0 : (m == 1) ? ka1 : (m == 2) ? ka2 : ka3;
#pragma unroll
    for (int r = 0; r < 16; ++r) {
      const float v = qa[r] * km[r];
      if (r < 4) zp0 += v;
      else if (r < 8) zp1 += v;
      else if (r < 12) zp2 += v;
      else zp3 += v;
    }
  }
  zp0 += __shfl_xor(zp0, 32);
  zp1 += __shfl_xor(zp1, 32);
  zp2 += __shfl_xor(zp2, 32);
  zp3 += __shfl_xor(zp3, 32);
  if (half == 0) {
    float4 v = {zp0 * SCALE, zp1 * SCALE, zp2 * SCALE, zp3 * SCALE};
    *(float4*)&z[(size_t)e * 4] = v;
  }
}

// ---------------------------------------------------------------------------
__global__ __launch_bounds__(256) void softmax_kernel(
    const float* __restrict__ z, const int* __restrict__ offs,
    float* __restrict__ out)
{
  const int node = blockIdx.x * 4 + (threadIdx.x >> 6);
  const int lane = threadIdx.x & 63;
  const int start = offs[node], end = offs[node + 1];
  if (start >= end) return;
  const int h = lane & 3, eo = lane >> 2;
  float m = -INFINITY;
  for (int e = start + eo; e < end; e += 16) m = fmaxf(m, z[(size_t)e * 4 + h]);
#pragma unroll
  for (int s = 4; s < 64; s <<= 1) m = fmaxf(m, __shfl_xor(m, s));
  float sum = 0.f;
  for (int e = start + eo; e < end; e += 16) sum += __expf(z[(size_t)e * 4 + h] - m);
#pragma unroll
  for (int s = 4; s < 64; s <<= 1) sum += __shfl_xor(sum, s);
  const float inv = 1.f / sum;
  for (int e = start + eo; e < end; e += 16)
    out[(size_t)e * 4 + h] = __expf(z[(size_t)e * 4 + h] - m) * inv;
}

extern "C" void kernel_launch(void* const* d_in, const int* in_sizes, int n_in,
                              void* d_out, int out_size, void* d_ws, size_t ws_size,
                              hipStream_t stream) {
  const float* x_q = (const float*)d_in[0];
  const float* x_k = (const float*)d_in[1];
  const float* emb = (const float*)d_in[2];
  const int* index = (const int*)d_in[3];
  const float* W_q = (const float*)d_in[4];
  const float* W_p = (const float*)d_in[5];
  float* out = (float*)d_out;

  char* ws = (char*)d_ws;
  float* z = (float*)ws;                                                    // 524288 B
  int* offs = (int*)(ws + 524288);                                          // 16388 B (pad 32 KB)
  unsigned short* fragWp = (unsigned short*)(ws + 524288 + 32768);          // 786432 B
  unsigned short* fragWq = (unsigned short*)(ws + 524288 + 32768 + 786432); // 14336 B

  prep_kernel<<<231, 256, 0, stream>>>(W_p, W_q, index, fragWp, fragWq, offs);
  main_kernel<<<256, 256, 0, stream>>>(x_q, x_k, emb, fragWp, fragWq, z);
  softmax_kernel<<<1024, 256, 0, stream>>>(z, offs, out);
}

// Round 7
// 134.448 us; speedup vs baseline: 1.2199x; 1.0274x over previous
//
#include <hip/hip_runtime.h>
#include <math.h>

#define E_TOTAL 32768
#define NUM_NODES 4096
#define SCALE 0.70710678118654752f

typedef __attribute__((ext_vector_type(8))) short bfrag;
typedef __attribute__((ext_vector_type(16))) float facc;

#define MFMA __builtin_amdgcn_mfma_f32_32x32x16_bf16

__device__ inline unsigned short f2bf(float f) {
  unsigned int u = __float_as_uint(f);
  unsigned int r = (u + 0x7FFFu + ((u >> 16) & 1u)) >> 16;
  return (unsigned short)r;
}
__device__ inline float bf2f(unsigned short s) {
  return __uint_as_float(((unsigned int)s) << 16);
}
__device__ inline void cvt8(const float* v, bfrag& hi, bfrag& lo) {
#pragma unroll
  for (int i = 0; i < 8; ++i) {
    unsigned short h = f2bf(v[i]);
    hi[i] = (short)h;
    lo[i] = (short)f2bf(v[i] - bf2f(h));
  }
}

// ---------------------------------------------------------------------------
// Combined prep: blocks 0..95 W_p frags, 96..102 W_q frags, 103..230 offsets
// frag layout per tile: [ks(4)][hl(2)][lane(64)][j(8)] bf16 (8 KB)
//   element = W_p[d][w*512 + c*32 + (lane&31)], d = ks*16 + (lane>>5)*8 + j
// NEW tile placement (m-split streams): slot = wslot[w] + c with
//   wslot = {w0:0, w1:64, w2:16, w3:80, w4:32, w5:48}
// -> wave pr=0 stream: slots 0..63  = [w0|w2|w4|w5] x16c  (m0 from w0,w2; m1 from w4,w5)
//    wave pr=1 stream: slots 64..95,32..63 = [w1|w3|w4|w5] (m2; m3)
// ---------------------------------------------------------------------------
__global__ __launch_bounds__(256) void prep_kernel(
    const float* __restrict__ Wp, const float* __restrict__ Wq,
    const int* __restrict__ index,
    unsigned short* __restrict__ fragWp, unsigned short* __restrict__ fragWq,
    int* __restrict__ offs)
{
  const int b = blockIdx.x, t = threadIdx.x;
  if (b < 96) {
    __shared__ unsigned short lds[4096];
    const int c = b / 6, w = b - c * 6;
    const int colbase = w * 512 + c * 32;
    const int cl = t & 31, dg = t >> 5;
#pragma unroll
    for (int i = 0; i < 8; ++i) {
      const int d = dg * 8 + i;
      const float v = Wp[(size_t)d * 3072 + colbase + cl];
      const unsigned short hi = f2bf(v);
      const unsigned short lo = f2bf(v - bf2f(hi));
      const int ks = d >> 4;
      const int lane = ((d >> 3) & 1) * 32 + cl;
      const int j = d & 7;
      lds[(ks * 2 + 0) * 512 + lane * 8 + j] = hi;
      lds[(ks * 2 + 1) * 512 + lane * 8 + j] = lo;
    }
    __syncthreads();
    const int wslot0 = (w == 0) ? 0 : (w == 1) ? 64 : (w == 2) ? 16
                     : (w == 3) ? 80 : (w == 4) ? 32 : 48;
    unsigned short* dst = fragWp + (size_t)(wslot0 + c) * 4096;
    ((uint4*)dst)[t] = ((const uint4*)lds)[t];
    ((uint4*)dst)[t + 256] = ((const uint4*)lds)[t + 256];
  } else if (b < 103) {
    const int slot = b - 96;
    const int w = (slot == 6) ? 5 : slot;
    const float sgn = (slot == 6) ? -1.f : 1.f;
    for (int tt = t; tt < 512; tt += 256) {
      const int lane = tt >> 3, j = tt & 7;
      const int o = lane & 31, c = (lane >> 5) * 8 + j;
      const float v = sgn * Wq[(size_t)(w * 16 + c) * 32 + o];
      const unsigned short hi = f2bf(v);
      const unsigned short lo = f2bf(v - bf2f(hi));
      fragWq[slot * 1024 + lane * 8 + j] = hi;
      fragWq[slot * 1024 + 512 + lane * 8 + j] = lo;
    }
  } else {
    const int tg = (b - 103) * 256 + t;
    if (tg >= E_TOTAL) return;
    const int cur = index[tg];
    const int prev = (tg == 0) ? -1 : index[tg - 1];
    for (int n = prev + 1; n <= cur; ++n) offs[n] = tg;
    if (tg == E_TOTAL - 1)
      for (int n = cur + 1; n <= NUM_NODES; ++n) offs[n] = E_TOTAL;
  }
}

// ---------------------------------------------------------------------------
// Main: 256 blocks (1/CU), 4 waves, 128 edges/block; each wave owns 64 edges
// (2 MFMA column-blocks) -> every A-fragment feeds 2 blocks = half the
// A-bytes/edge (2 MB/CU vs round-0's 3 MB at the measured ~24.5 B/cyc wall).
// Wave pair splits by M: pr0 -> m0 (w0,w2) + m1 (w4,w5); pr1 -> m2 + m3.
// Uniform stream: 64 tiles, each -> ONE accumulator with ONE scalar (signs
// folded per parity). Single merged 12-MFMA chain per edge-block (cc0+cc1+cc2
// in one acc, R1-verified), two independent chains interleaved for ILP.
// Direct global->VGPR, zero barriers in the loop, ~225 VGPRs (no spill).
// z is linear in m -> cross-pair zp reduce via LDS at the end.
// ---------------------------------------------------------------------------
__global__ __launch_bounds__(256, 1) void main_kernel(
    const float* __restrict__ x_q, const float* __restrict__ x_k,
    const float* __restrict__ emb,
    const unsigned short* __restrict__ fragWp,
    const unsigned short* __restrict__ fragWq,
    float* __restrict__ z)
{
  __shared__ float xk_t[64][129];   // 33 KB, padded
  __shared__ float zred[4][64][4];  // 4 KB

  const int t = threadIdx.x;
  const int lane = t & 63, wv = t >> 6;
  const int pr = wv & 1, pairI = wv >> 1;
  const int col = lane & 31, half = lane >> 5;
  const int eb = blockIdx.x * 128;
  const int el0 = pairI * 64 + col;   // edge within block, column-block a
  const int el1 = el0 + 32;           // column-block b
  const int e0 = eb + el0, e1 = eb + el1;

  // stage x_k transposed: thread t -> edge t&127, d-half (t>>7)*32
  {
    const int er = t & 127, dh = (t >> 7) * 32;
    const float* src = x_k + (size_t)(eb + er) * 64 + dh;
#pragma unroll
    for (int i = 0; i < 8; ++i) {
      float4 v = *(const float4*)(src + i * 4);
      xk_t[dh + i * 4 + 0][er] = v.x;
      xk_t[dh + i * 4 + 1][er] = v.y;
      xk_t[dh + i * 4 + 2][er] = v.z;
      xk_t[dh + i * 4 + 3][er] = v.w;
    }
  }

  // emb B-fragments hi/lo for BOTH 32-edge column blocks
  bfrag ebh0[4], ebl0[4], ebh1[4], ebl1[4];
#pragma unroll
  for (int ks = 0; ks < 4; ++ks) {
    float tmp[8];
    *(float4*)&tmp[0] = *(const float4*)(emb + (size_t)e0 * 64 + ks * 16 + half * 8);
    *(float4*)&tmp[4] = *(const float4*)(emb + (size_t)e0 * 64 + ks * 16 + half * 8 + 4);
    cvt8(tmp, ebh0[ks], ebl0[ks]);
    *(float4*)&tmp[0] = *(const float4*)(emb + (size_t)e1 * 64 + ks * 16 + half * 8);
    *(float4*)&tmp[4] = *(const float4*)(emb + (size_t)e1 * 64 + ks * 16 + half * 8 + 4);
    cvt8(tmp, ebh1[ks], ebl1[ks]);
  }

  facc kaP0 = {0}, kaQ0 = {0}, kaP1 = {0}, kaQ1 = {0};

  __syncthreads();  // xk_t ready (only barrier before the end)

  // per-parity stream quarters (tile units -> shorts) and scalar rows
  const unsigned short* fb = fragWp + lane * 8;
  const int qb0 = (pr ? 64 : 0) * 4096;   // w1 : w0  -> kaP, scalar x0 (row c)
  const int qb1 = (pr ? 80 : 16) * 4096;  // w3 : w2  -> kaP, scalar x2 (row 32+c)
  const int qb2 = 32 * 4096;              // w4       -> kaQ, x3 : x1
  const int qb3 = 48 * 4096;              // w5       -> kaQ, -x1 : x3
  const int r2 = pr ? 48 : 16;
  const int r3 = pr ? 16 : 48;
  const float sg3 = pr ? -1.f : 1.f;

#define TILE(WB, XA, XB, KA, KB)                                              \
  {                                                                           \
    const unsigned short* wb_ = (WB);                                         \
    bfrag fh[4], fl[4];                                                       \
    _Pragma("unroll")                                                         \
    for (int ks = 0; ks < 4; ++ks) {                                          \
      *(uint4*)&fh[ks] = *(const uint4*)(wb_ + ks * 1024);                    \
      *(uint4*)&fl[ks] = *(const uint4*)(wb_ + ks * 1024 + 512);              \
    }                                                                         \
    facc cc = {0.f}, cd = {0.f};                                              \
    _Pragma("unroll")                                                         \
    for (int ks = 0; ks < 4; ++ks) {                                          \
      cc = MFMA(fh[ks], ebh0[ks], cc, 0, 0, 0);                               \
      cd = MFMA(fh[ks], ebh1[ks], cd, 0, 0, 0);                               \
      cc = MFMA(fh[ks], ebl0[ks], cc, 0, 0, 0);                               \
      cd = MFMA(fh[ks], ebl1[ks], cd, 0, 0, 0);                               \
      cc = MFMA(fl[ks], ebh0[ks], cc, 0, 0, 0);                               \
      cd = MFMA(fl[ks], ebh1[ks], cd, 0, 0, 0);                               \
    }                                                                         \
    _Pragma("unroll")                                                         \
    for (int r = 0; r < 16; ++r) {                                            \
      (KA)[r] = fmaf((XA), cc[r], (KA)[r]);                                   \
      (KB)[r] = fmaf((XB), cd[r], (KB)[r]);                                   \
    }                                                                         \
  }

  for (int c = 0; c < 16; ++c) {
    const float xs0a = xk_t[c][el0],          xs0b = xk_t[c][el1];
    const float xs1a = xk_t[32 + c][el0],     xs1b = xk_t[32 + c][el1];
    const float xs2a = xk_t[r2 + c][el0],     xs2b = xk_t[r2 + c][el1];
    const float xs3a = sg3 * xk_t[r3 + c][el0], xs3b = sg3 * xk_t[r3 + c][el1];
    TILE(fb + qb0 + c * 4096, xs0a, xs0b, kaP0, kaP1)
    TILE(fb + qb1 + c * 4096, xs1a, xs1b, kaP0, kaP1)
    TILE(fb + qb2 + c * 4096, xs2a, xs2b, kaQ0, kaQ1)
    TILE(fb + qb3 + c * 4096, xs3a, xs3b, kaQ0, kaQ1)
  }
#undef TILE

  // ---- q via MFMA (C layout matches ka); this wave covers only its 2 m's,
  //      for both edge blocks; cross-pair sum completes z.
#define QTERM(QA_, A_, S_)                                                    \
  {                                                                           \
    bfrag wh, wl;                                                             \
    *(uint4*)&wh = *(const uint4*)(fragWq + (S_)*1024 + lane * 8);            \
    *(uint4*)&wl = *(const uint4*)(fragWq + (S_)*1024 + 512 + lane * 8);      \
    QA_ = MFMA(wh, xqh[A_], QA_, 0, 0, 0);                                    \
    QA_ = MFMA(wh, xql[A_], QA_, 0, 0, 0);                                    \
    QA_ = MFMA(wl, xqh[A_], QA_, 0, 0, 0);                                    \
  }

#pragma unroll
  for (int blk = 0; blk < 2; ++blk) {
    const int e = blk ? e1 : e0;
    bfrag xqh[4], xql[4];
#pragma unroll
    for (int a = 0; a < 4; ++a) {
      float tmp[8];
      *(float4*)&tmp[0] = *(const float4*)(x_q + (size_t)e * 64 + a * 16 + half * 8);
      *(float4*)&tmp[4] = *(const float4*)(x_q + (size_t)e * 64 + a * 16 + half * 8 + 4);
      cvt8(tmp, xqh[a], xql[a]);
    }
    facc qaP = {0.f}, qaQ = {0.f};
    if (pr == 0) {
      QTERM(qaP, 0, 0) QTERM(qaP, 2, 2)   // m0: Wq0*xq0 + Wq2*xq2
      QTERM(qaQ, 1, 4) QTERM(qaQ, 3, 5)   // m1: Wq4*xq1 + Wq5*xq3
    } else {
      QTERM(qaP, 0, 1) QTERM(qaP, 2, 3)   // m2: Wq1*xq0 + Wq3*xq2
      QTERM(qaQ, 3, 4) QTERM(qaQ, 1, 6)   // m3: Wq4*xq3 - Wq5*xq1 (slot6=-Wq5)
    }
    const facc& kp = blk ? kaP1 : kaP0;
    const facc& kq = blk ? kaQ1 : kaQ0;
    float zp0 = 0.f, zp1 = 0.f, zp2 = 0.f, zp3 = 0.f;
#pragma unroll
    for (int r = 0; r < 16; ++r) {
      const float v = qaP[r] * kp[r] + qaQ[r] * kq[r];
      if (r < 4) zp0 += v;
      else if (r < 8) zp1 += v;
      else if (r < 12) zp2 += v;
      else zp3 += v;
    }
    zp0 += __shfl_xor(zp0, 32);
    zp1 += __shfl_xor(zp1, 32);
    zp2 += __shfl_xor(zp2, 32);
    zp3 += __shfl_xor(zp3, 32);
    if (half == 0) {
      float4 v = {zp0, zp1, zp2, zp3};
      *(float4*)&zred[wv][blk * 32 + col][0] = v;
    }
  }
#undef QTERM

  __syncthreads();
  if (pr == 0 && half == 0) {
#pragma unroll
    for (int blk = 0; blk < 2; ++blk) {
      const int idx = blk * 32 + col;
      float4 a = *(const float4*)&zred[wv][idx][0];
      float4 b = *(const float4*)&zred[wv ^ 1][idx][0];
      float4 o = {(a.x + b.x) * SCALE, (a.y + b.y) * SCALE,
                  (a.z + b.z) * SCALE, (a.w + b.w) * SCALE};
      *(float4*)&z[(size_t)(eb + pairI * 64 + idx) * 4] = o;
    }
  }
}

// ---------------------------------------------------------------------------
__global__ __launch_bounds__(256) void softmax_kernel(
    const float* __restrict__ z, const int* __restrict__ offs,
    float* __restrict__ out)
{
  const int node = blockIdx.x * 4 + (threadIdx.x >> 6);
  const int lane = threadIdx.x & 63;
  const int start = offs[node], end = offs[node + 1];
  if (start >= end) return;
  const int h = lane & 3, eo = lane >> 2;
  float m = -INFINITY;
  for (int e = start + eo; e < end; e += 16) m = fmaxf(m, z[(size_t)e * 4 + h]);
#pragma unroll
  for (int s = 4; s < 64; s <<= 1) m = fmaxf(m, __shfl_xor(m, s));
  float sum = 0.f;
  for (int e = start + eo; e < end; e += 16) sum += __expf(z[(size_t)e * 4 + h] - m);
#pragma unroll
  for (int s = 4; s < 64; s <<= 1) sum += __shfl_xor(sum, s);
  const float inv = 1.f / sum;
  for (int e = start + eo; e < end; e += 16)
    out[(size_t)e * 4 + h] = __expf(z[(size_t)e * 4 + h] - m) * inv;
}

extern "C" void kernel_launch(void* const* d_in, const int* in_sizes, int n_in,
                              void* d_out, int out_size, void* d_ws, size_t ws_size,
                              hipStream_t stream) {
  const float* x_q = (const float*)d_in[0];
  const float* x_k = (const float*)d_in[1];
  const float* emb = (const float*)d_in[2];
  const int* index = (const int*)d_in[3];
  const float* W_q = (const float*)d_in[4];
  const float* W_p = (const float*)d_in[5];
  float* out = (float*)d_out;

  char* ws = (char*)d_ws;
  float* z = (float*)ws;                                                    // 524288 B
  int* offs = (int*)(ws + 524288);                                          // 16388 B (pad 32 KB)
  unsigned short* fragWp = (unsigned short*)(ws + 524288 + 32768);          // 786432 B
  unsigned short* fragWq = (unsigned short*)(ws + 524288 + 32768 + 786432); // 14336 B

  prep_kernel<<<231, 256, 0, stream>>>(W_p, W_q, index, fragWp, fragWq, offs);
  main_kernel<<<256, 256, 0, stream>>>(x_q, x_k, emb, fragWp, fragWq, z);
  softmax_kernel<<<1024, 256, 0, stream>>>(z, offs, out);
}